// Round 1
// 20417.839 us; speedup vs baseline: 1.2741x; 1.2741x over previous
//
#include <hip/hip_runtime.h>
#include <math.h>

// PhysicsLSGStep: bitwise-faithful f32 replication of the numpy reference
// (model H11, PASSED @ absmax 0.484375 — arithmetic order is UNCHANGED here).
// R12: memory-pattern round.
//  - k_perm: one-shot permutation of per-edge operands (src, dst, 1/dx, dz/dx)
//    into CSR order => CG-loop kernels read coalesced streams, no edge-id
//    indirection (was: random 4B gathers via dstList/srcList each iteration).
//  - k_d1w/k_d1tz/k_slope_b: float4 feature vectorization (thread = node x
//    feature-half). Per-feature op order identical; features are independent.
//  - k_dot: leaf staged into padded LDS with coalesced loads (was: 512B lane
//    stride, ~64 lines per wave load). pw_base op sequence identical, from LDS.
// Scatter sums stay in sorted-edge-id (CSR) order; dots replay the exact
// numpy pairwise tree. Elementwise: f32 __f*_rn, no FMA contraction.

#define F 8
#define CG_ITERS 30
#define LEAF_T 4096
#define LEAF_PAD (LEAF_T + LEAF_T / 128 + 8)
#define DOT_NB 800     // >= max leaves (NL = 512 for NF-1 = 1,599,999)

#define S_RS    0
#define S_ALPHA 1
#define S_BETA  2
#define S_DONE  3
#define S_DONE2 4

__device__ __forceinline__ float dt_eff_of(const float* dtp) {
    return fminf(fmaxf(dtp[0], 0.02f), 2.0f);
}

// ---------- numpy pairwise sum base block from padded LDS (n<=128) ----------
// identical op order to the original pw_base; only the load source changed.

__device__ __forceinline__ float pw_base_lds(const float* sA, const float* sB,
                                             int off, int n) {
#define AV(i) sA[(off + (i)) + ((off + (i)) >> 7)]
#define BV(i) sB[(off + (i)) + ((off + (i)) >> 7)]
    if (n < 8) {
        float res = 0.f;
        for (int i = 0; i < n; ++i) res = __fadd_rn(res, __fmul_rn(AV(i), BV(i)));
        return res;
    }
    float r0 = __fmul_rn(AV(0), BV(0));
    float r1 = __fmul_rn(AV(1), BV(1));
    float r2 = __fmul_rn(AV(2), BV(2));
    float r3 = __fmul_rn(AV(3), BV(3));
    float r4 = __fmul_rn(AV(4), BV(4));
    float r5 = __fmul_rn(AV(5), BV(5));
    float r6 = __fmul_rn(AV(6), BV(6));
    float r7 = __fmul_rn(AV(7), BV(7));
    int i = 8;
    int lim = n - (n & 7);
    for (; i < lim; i += 8) {
        r0 = __fadd_rn(r0, __fmul_rn(AV(i + 0), BV(i + 0)));
        r1 = __fadd_rn(r1, __fmul_rn(AV(i + 1), BV(i + 1)));
        r2 = __fadd_rn(r2, __fmul_rn(AV(i + 2), BV(i + 2)));
        r3 = __fadd_rn(r3, __fmul_rn(AV(i + 3), BV(i + 3)));
        r4 = __fadd_rn(r4, __fmul_rn(AV(i + 4), BV(i + 4)));
        r5 = __fadd_rn(r5, __fmul_rn(AV(i + 5), BV(i + 5)));
        r6 = __fadd_rn(r6, __fmul_rn(AV(i + 6), BV(i + 6)));
        r7 = __fadd_rn(r7, __fmul_rn(AV(i + 7), BV(i + 7)));
    }
    float res = __fadd_rn(__fadd_rn(__fadd_rn(r0, r1), __fadd_rn(r2, r3)),
                          __fadd_rn(__fadd_rn(r4, r5), __fadd_rn(r6, r7)));
    for (; i < n; ++i) res = __fadd_rn(res, __fmul_rn(AV(i), BV(i)));
    return res;
#undef AV
#undef BV
}

// leaf decomposition of virtual [0, n) (n = NF-1; physical offset +1).
__global__ void k_build_leaves(int n, int* leafOff, int* leafN, int* nLeaf) {
    __shared__ int spOff[40], spN[40];
    if (threadIdx.x != 0 || blockIdx.x != 0) return;
    int sp = 0;
    spOff[0] = 0; spN[0] = n;
    int cnt = 0;
    while (sp >= 0) {
        int off = spOff[sp], nn = spN[sp]; sp--;
        if (nn <= LEAF_T) {
            if (cnt < 2048) { leafOff[cnt] = off; leafN[cnt] = nn; }
            cnt++;
        } else {
            int n2 = nn / 2; n2 -= (n2 & 7);
            spOff[++sp] = off + n2; spN[sp] = nn - n2;  // right (popped second)
            spOff[++sp] = off;      spN[sp] = n2;       // left  (popped first)
        }
    }
    *nLeaf = cnt;
}

// full dot: one wave per leaf + last-block upper-tree combine + scalar update.
// R12: leaf values staged through padded LDS (coalesced); tree replay unchanged.
__global__ void k_dot(const float* __restrict__ a, const float* __restrict__ b,
                      const int* __restrict__ leafOff, const int* __restrict__ leafN,
                      const int* __restrict__ nLeaf, float* __restrict__ partial,
                      int* __restrict__ ctr, float* __restrict__ scal,
                      int n, int mode, int nBlocks) {
    __shared__ int   sOff[64], sN[64];     // base blocks of this leaf (<=64)
    __shared__ float sBase[64];            // base-block partial values
    __shared__ int   wSo[16], wSn[16], wSt[16];
    __shared__ float wVal[16];
    __shared__ int   sNB;
    __shared__ int   isLast;
    __shared__ float lp[1024];
    __shared__ int   cSn[24], cSt[24];
    __shared__ float cVal[24];
    __shared__ float sA[LEAF_PAD], sB[LEAF_PAD];

    int j = blockIdx.x, lane = threadIdx.x;
    int NL = *nLeaf;
    if (j < NL) {
        int P = leafOff[j] + 1;    // physical start of this leaf
        int nn = leafN[j];
        // coalesced stage: global (stride-64 across lanes) -> padded LDS
        for (int g = lane; g < nn; g += 64) {
            float av = a[P + g], bv = b[P + g];
            int m = g + (g >> 7);
            sA[m] = av; sB[m] = bv;
        }
        if (lane == 0) {
            // phase 1: enumerate base blocks in order (leaf-relative offsets)
            int coff = 0, cn = nn;
            int sp = 0, cnt = 0;
            for (;;) {
                if (cn <= 128) {
                    sOff[cnt] = coff; sN[cnt] = cn; cnt++;
                    bool fin = false;
                    for (;;) {
                        if (sp == 0) { fin = true; break; }
                        if (wSt[sp - 1] == 0) {
                            wSt[sp - 1] = 1;
                            int n2 = wSn[sp - 1] / 2; n2 -= (n2 & 7);
                            coff = wSo[sp - 1] + n2; cn = wSn[sp - 1] - n2;
                            break;
                        } else sp--;
                    }
                    if (fin) break;
                } else {
                    wSo[sp] = coff; wSn[sp] = cn; wSt[sp] = 0; sp++;
                    int n2 = cn / 2; n2 -= (n2 & 7);
                    cn = n2;
                }
            }
            sNB = cnt;
        }
        __syncthreads();
        int NB = sNB;
        if (lane < NB) sBase[lane] = pw_base_lds(sA, sB, sOff[lane], sN[lane]);
        __syncthreads();
        if (lane == 0) {
            // phase 2: replay combine tree, popping base values in order
            int sp = 0, cn = leafN[j], c2 = 0;
            float res;
            for (;;) {
                if (cn <= 128) {
                    float val = sBase[c2++];
                    bool done = false;
                    for (;;) {
                        if (sp == 0) { res = val; done = true; break; }
                        if (wSt[sp - 1] == 0) {
                            wSt[sp - 1] = 1; wVal[sp - 1] = val;
                            int n2 = wSn[sp - 1] / 2; n2 -= (n2 & 7);
                            cn = wSn[sp - 1] - n2;
                            break;
                        } else { val = __fadd_rn(wVal[sp - 1], val); sp--; }
                    }
                    if (done) break;
                } else {
                    wSn[sp] = cn; wSt[sp] = 0; sp++;
                    int n2 = cn / 2; n2 -= (n2 & 7);
                    cn = n2;
                }
            }
            partial[j] = res;
        }
    }
    __threadfence();
    if (lane == 0) isLast = (atomicAdd(ctr, 1) == nBlocks - 1) ? 1 : 0;
    __syncthreads();
    if (!isLast) return;
    __threadfence();
    for (int k = lane; k < NL; k += 64) lp[k] = partial[k];
    __syncthreads();
    if (lane != 0) return;
    // upper-tree combine (exact pairwise recursion over virtual n, leaves=lp)
    int cnt = 0;
    int sp = 0, cn = n;
    float res;
    for (;;) {
        if (cn <= LEAF_T) {
            float val = lp[cnt++];
            bool ret = false;
            for (;;) {
                if (sp == 0) { res = val; ret = true; break; }
                if (cSt[sp - 1] == 0) {
                    cSt[sp - 1] = 1; cVal[sp - 1] = val;
                    int n2 = cSn[sp - 1] / 2; n2 -= (n2 & 7);
                    cn = cSn[sp - 1] - n2;
                    break;
                } else { val = __fadd_rn(cVal[sp - 1], val); sp--; }
            }
            if (ret) break;
        } else {
            cSn[sp] = cn; cSt[sp] = 0; sp++;
            int n2 = cn / 2; n2 -= (n2 & 7);
            cn = n2;
        }
    }
    res = __fadd_rn(__fmul_rn(a[0], b[0]), res);   // first-element init
    if (mode == 0) {
        scal[S_RS] = res; scal[S_DONE] = 0.f; scal[S_DONE2] = 0.f;
    } else if (mode == 1) {
        scal[S_DONE] = scal[S_DONE2];  // done_old for this iteration
        scal[S_ALPHA] = __fdiv_rn(scal[S_RS], __fadd_rn(res, (float)1e-12));
    } else {
        float rs1 = res;
        scal[S_BETA] = __fdiv_rn(rs1, __fadd_rn(scal[S_RS], (float)1e-12));
        float dn = scal[S_DONE];
        if (dn == 0.f) scal[S_RS] = rs1;
        scal[S_DONE2] = (dn != 0.f || __fsqrt_rn(rs1) <= (float)1e-4) ? 1.f : 0.f;
    }
    *ctr = 0;   // reset for next dot in the graph
}

// ---------- CSR build (stable in edge order) ----------

__global__ void k_edge_pre(const int* __restrict__ dst, const int* __restrict__ src,
                           int* __restrict__ dstCnt, int* __restrict__ srcCnt, int E) {
    int e = blockIdx.x * blockDim.x + threadIdx.x;
    if (e >= E) return;
    atomicAdd(&dstCnt[dst[e]], 1);
    atomicAdd(&srcCnt[src[e]], 1);
}

__global__ void k_scan1(const int* __restrict__ cnt, int* __restrict__ incl,
                        int* __restrict__ bsums, int N) {
    __shared__ int sm[512];
    int i = blockIdx.x * 512 + threadIdx.x;
    sm[threadIdx.x] = (i < N) ? cnt[i] : 0;
    __syncthreads();
    for (int off = 1; off < 512; off <<= 1) {
        int t = (threadIdx.x >= off) ? sm[threadIdx.x - off] : 0;
        __syncthreads();
        sm[threadIdx.x] += t;
        __syncthreads();
    }
    if (i < N) incl[i] = sm[threadIdx.x];
    if (threadIdx.x == 511) bsums[blockIdx.x] = sm[511];
}

__global__ void k_scan2(int* __restrict__ bsums, int nb) {
    __shared__ int sm[512];
    sm[threadIdx.x] = (threadIdx.x < nb) ? bsums[threadIdx.x] : 0;
    __syncthreads();
    for (int off = 1; off < 512; off <<= 1) {
        int t = (threadIdx.x >= off) ? sm[threadIdx.x - off] : 0;
        __syncthreads();
        sm[threadIdx.x] += t;
        __syncthreads();
    }
    if (threadIdx.x < nb) bsums[threadIdx.x] = sm[threadIdx.x];
}

__global__ void k_scan3(int* __restrict__ off, const int* __restrict__ bsums,
                        const int* __restrict__ cnt, int N, int E) {
    int i = blockIdx.x * 512 + threadIdx.x;
    if (i < N) {
        int add = (blockIdx.x > 0) ? bsums[blockIdx.x - 1] : 0;
        off[i] = off[i] + add - cnt[i];  // exclusive
    }
    if (i == 0) off[N] = E;
}

__global__ void k_fill(const int* __restrict__ dst, const int* __restrict__ src,
                       const int* __restrict__ dstOff, const int* __restrict__ srcOff,
                       int* __restrict__ cursD, int* __restrict__ cursS,
                       int* __restrict__ dstList, int* __restrict__ srcList, int E) {
    int e = blockIdx.x * blockDim.x + threadIdx.x;
    if (e >= E) return;
    int d = dst[e];
    dstList[dstOff[d] + atomicAdd(&cursD[d], 1)] = e;
    int s0 = src[e];
    srcList[srcOff[s0] + atomicAdd(&cursS[s0], 1)] = e;
}

__device__ __forceinline__ void insort(int* L, int lo, int hi) {
    for (int a = lo + 1; a < hi; ++a) {
        int key = L[a]; int b = a - 1;
        while (b >= lo && L[b] > key) { L[b + 1] = L[b]; b--; }
        L[b + 1] = key;
    }
}

__global__ void k_sort(const int* __restrict__ dstOff, const int* __restrict__ srcOff,
                       int* __restrict__ dstList, int* __restrict__ srcList, int N) {
    int i = blockIdx.x * blockDim.x + threadIdx.x;
    if (i >= N) return;
    insort(dstList, dstOff[i], dstOff[i + 1]);
    insort(srcList, srcOff[i], srcOff[i + 1]);
}

// R12: permute per-edge operands into CSR (sorted-edge-id) order, once.
// Values computed with the exact ops the loop kernels used before
// (fmaxf + __fdiv_rn), so downstream arithmetic is bitwise identical.
__global__ void k_perm(const int* __restrict__ dstList, const int* __restrict__ srcList,
                       const int* __restrict__ srcp, const int* __restrict__ dstp,
                       const float* __restrict__ ea,
                       int* __restrict__ srcA, float* __restrict__ invD,
                       float* __restrict__ slopeD,
                       int* __restrict__ dstB, float* __restrict__ invS, int E) {
    int k = blockIdx.x * blockDim.x + threadIdx.x;
    if (k >= E) return;
    int e = dstList[k];
    float dx = fmaxf(ea[2 * e], 1e-6f);
    srcA[k]   = srcp[e];
    invD[k]   = __fdiv_rn(1.f, dx);
    slopeD[k] = __fdiv_rn(ea[2 * e + 1], dx);
    int e2 = srcList[k];
    float dx2 = fmaxf(ea[2 * e2], 1e-6f);
    dstB[k] = dstp[e2];
    invS[k] = __fdiv_rn(1.f, dx2);
}

// ---------- physics kernels (exact np op order, f32 sequential) ----------

// slope_n (sequential, CSR edge order); b = u - (dt*g)*slope_n -> r ; y = u*b
__global__ void k_slope_b(const float* __restrict__ u, const float* __restrict__ slopeD,
                          const int* __restrict__ dstOff,
                          float* __restrict__ r, float* __restrict__ y,
                          const float* __restrict__ dtp, const float* __restrict__ gp,
                          int N) {
    int i = blockIdx.x * blockDim.x + threadIdx.x;
    if (i >= N) return;
    float dtg = __fmul_rn(dt_eff_of(dtp), gp[0]);
    float sn = 0.f;
    int k0 = dstOff[i], k1 = dstOff[i + 1];
    for (int k = k0; k < k1; ++k) sn = __fadd_rn(sn, slopeD[k]);
    float ms = __fmul_rn(dtg, sn);
    const float4* u4 = (const float4*)u;
    float4* r4 = (float4*)r;
    float4* y4 = (float4*)y;
    #pragma unroll
    for (int hh = 0; hh < 2; ++hh) {
        float4 uv = u4[i * 2 + hh];
        float4 bv;
        bv.x = __fsub_rn(uv.x, ms);
        bv.y = __fsub_rn(uv.y, ms);
        bv.z = __fsub_rn(uv.z, ms);
        bv.w = __fsub_rn(uv.w, ms);
        r4[i * 2 + hh] = bv;
        float4 yv;
        yv.x = __fmul_rn(uv.x, bv.x);
        yv.y = __fmul_rn(uv.y, bv.y);
        yv.z = __fmul_rn(uv.z, bv.z);
        yv.w = __fmul_rn(uv.w, bv.w);
        y4[i * 2 + hh] = yv;
    }
}

// D1_T via y (= u*input), then out = base + dt*acc.  thread = (node, f-half).
// Setup: base=r(b), out=p. Loop: base=w, out=t(z).
__global__ void k_d1tz(const int* __restrict__ dstB, const int* __restrict__ dstOff,
                       const float* __restrict__ invD, const int* __restrict__ srcOff,
                       const float* __restrict__ invS, const float* __restrict__ y,
                       const float* __restrict__ base, float* __restrict__ out,
                       const float* __restrict__ dtp, int N2) {
    int idx2 = blockIdx.x * blockDim.x + threadIdx.x;
    if (idx2 >= N2) return;
    int i = idx2 >> 1, h = idx2 & 1;
    const float4* y4 = (const float4*)y;
    float4 uy = y4[idx2];
    float4 acc = make_float4(0.f, 0.f, 0.f, 0.f);
    int k0 = dstOff[i], k1 = dstOff[i + 1];
    for (int k = k0; k < k1; ++k) {
        float iv = invD[k];
        acc.x = __fadd_rn(acc.x, __fmul_rn(uy.x, iv));
        acc.y = __fadd_rn(acc.y, __fmul_rn(uy.y, iv));
        acc.z = __fadd_rn(acc.z, __fmul_rn(uy.z, iv));
        acc.w = __fadd_rn(acc.w, __fmul_rn(uy.w, iv));
    }
    k0 = srcOff[i]; k1 = srcOff[i + 1];
    for (int k = k0; k < k1; ++k) {
        int d = dstB[k];
        float iv = invS[k];
        float4 yd = y4[d * 2 + h];
        float t0 = __fmul_rn(yd.x, iv); acc.x = __fadd_rn(acc.x, -t0);
        float t1 = __fmul_rn(yd.y, iv); acc.y = __fadd_rn(acc.y, -t1);
        float t2 = __fmul_rn(yd.z, iv); acc.z = __fadd_rn(acc.z, -t2);
        float t3 = __fmul_rn(yd.w, iv); acc.w = __fadd_rn(acc.w, -t3);
    }
    float dt = dt_eff_of(dtp);
    float4 bs = ((const float4*)base)[idx2];
    float4 ov;
    ov.x = __fadd_rn(bs.x, __fmul_rn(dt, acc.x));
    ov.y = __fadd_rn(bs.y, __fmul_rn(dt, acc.y));
    ov.z = __fadd_rn(bs.z, __fmul_rn(dt, acc.z));
    ov.w = __fadd_rn(bs.w, __fmul_rn(dt, acc.w));
    ((float4*)out)[idx2] = ov;
}

// r = p copy ; x = 0  (float4)
__global__ void k_init(const float4* __restrict__ p4, float4* __restrict__ r4,
                       float4* __restrict__ x4, int n4) {
    int i = blockIdx.x * blockDim.x + threadIdx.x;
    if (i >= n4) return;
    r4[i] = p4[i];
    x4[i] = make_float4(0.f, 0.f, 0.f, 0.f);
}

// D1(p) fused with w = p + dt*(u*t) and y = u*w.  thread = (node, f-half).
__global__ void k_d1w(const int* __restrict__ srcA, const int* __restrict__ dstOff,
                      const float* __restrict__ invD, const float* __restrict__ pv,
                      const float* __restrict__ u,
                      float* __restrict__ w, float* __restrict__ y,
                      const float* __restrict__ dtp, int N2) {
    int idx2 = blockIdx.x * blockDim.x + threadIdx.x;
    if (idx2 >= N2) return;
    int i = idx2 >> 1, h = idx2 & 1;
    const float4* pv4 = (const float4*)pv;
    float4 pi = pv4[idx2];
    float4 acc = make_float4(0.f, 0.f, 0.f, 0.f);
    int k0 = dstOff[i], k1 = dstOff[i + 1];
    for (int k = k0; k < k1; ++k) {
        int s = srcA[k];
        float iv = invD[k];
        float4 ps = pv4[s * 2 + h];
        acc.x = __fadd_rn(acc.x, __fmul_rn(__fsub_rn(pi.x, ps.x), iv));
        acc.y = __fadd_rn(acc.y, __fmul_rn(__fsub_rn(pi.y, ps.y), iv));
        acc.z = __fadd_rn(acc.z, __fmul_rn(__fsub_rn(pi.z, ps.z), iv));
        acc.w = __fadd_rn(acc.w, __fmul_rn(__fsub_rn(pi.w, ps.w), iv));
    }
    float dt = dt_eff_of(dtp);
    float4 uv = ((const float4*)u)[idx2];
    float4 wv;
    wv.x = __fadd_rn(pi.x, __fmul_rn(dt, __fmul_rn(uv.x, acc.x)));
    wv.y = __fadd_rn(pi.y, __fmul_rn(dt, __fmul_rn(uv.y, acc.y)));
    wv.z = __fadd_rn(pi.z, __fmul_rn(dt, __fmul_rn(uv.z, acc.z)));
    wv.w = __fadd_rn(pi.w, __fmul_rn(dt, __fmul_rn(uv.w, acc.w)));
    ((float4*)w)[idx2] = wv;
    float4 yv;
    yv.x = __fmul_rn(uv.x, wv.x);
    yv.y = __fmul_rn(uv.y, wv.y);
    yv.z = __fmul_rn(uv.z, wv.z);
    yv.w = __fmul_rn(uv.w, wv.w);
    ((float4*)y)[idx2] = yv;
}

// x += alpha*p ; r -= alpha*z   (guarded by done_old)  float4
__global__ void k_xr(float4* __restrict__ x4, float4* __restrict__ r4,
                     const float4* __restrict__ p4, const float4* __restrict__ z4,
                     const float* __restrict__ scal, int n4) {
    int i = blockIdx.x * blockDim.x + threadIdx.x;
    if (i >= n4) return;
    if (scal[S_DONE] != 0.f) return;
    float al = scal[S_ALPHA];
    float4 xv = x4[i], pv = p4[i], rv = r4[i], zv = z4[i];
    xv.x = __fadd_rn(xv.x, __fmul_rn(al, pv.x));
    xv.y = __fadd_rn(xv.y, __fmul_rn(al, pv.y));
    xv.z = __fadd_rn(xv.z, __fmul_rn(al, pv.z));
    xv.w = __fadd_rn(xv.w, __fmul_rn(al, pv.w));
    rv.x = __fsub_rn(rv.x, __fmul_rn(al, zv.x));
    rv.y = __fsub_rn(rv.y, __fmul_rn(al, zv.y));
    rv.z = __fsub_rn(rv.z, __fmul_rn(al, zv.z));
    rv.w = __fsub_rn(rv.w, __fmul_rn(al, zv.w));
    x4[i] = xv;
    r4[i] = rv;
}

// p = r + beta*p   (guarded by done_old)  float4
__global__ void k_p(float4* __restrict__ p4, const float4* __restrict__ r4,
                    const float* __restrict__ scal, int n4) {
    int i = blockIdx.x * blockDim.x + threadIdx.x;
    if (i >= n4) return;
    if (scal[S_DONE] != 0.f) return;
    float be = scal[S_BETA];
    float4 pv = p4[i], rv = r4[i];
    pv.x = __fadd_rn(rv.x, __fmul_rn(be, pv.x));
    pv.y = __fadd_rn(rv.y, __fmul_rn(be, pv.y));
    pv.z = __fadd_rn(rv.z, __fmul_rn(be, pv.z));
    pv.w = __fadd_rn(rv.w, __fmul_rn(be, pv.w));
    p4[i] = pv;
}

extern "C" void kernel_launch(void* const* d_in, const int* in_sizes, int n_in,
                              void* d_out, int out_size, void* d_ws, size_t ws_size,
                              hipStream_t stream) {
    const float* u   = (const float*)d_in[0];
    const int*   ei  = (const int*)d_in[1];
    const float* ea  = (const float*)d_in[2];
    const float* dtp = (const float*)d_in[3];
    const float* gp  = (const float*)d_in[4];

    const int NF = in_sizes[0];        // 1,600,000
    const int N  = NF / F;             // 200,000
    const int E  = in_sizes[2] / 2;    // 3,200,000
    const int* srcp = ei;
    const int* dstp = ei + E;

    char* wp = (char*)d_ws;
    float* scal    = (float*)wp; wp += 64 * 4;     // scal[0..7] + ctr @ int slot 32
    float* r       = (float*)wp; wp += (size_t)NF * 4;
    float* p       = (float*)wp; wp += (size_t)NF * 4;
    float* t       = (float*)wp; wp += (size_t)NF * 4;   // z
    float* w       = (float*)wp; wp += (size_t)NF * 4;
    float* y       = (float*)wp; wp += (size_t)NF * 4;   // u*w / u*b
    int*   dstList = (int*)wp;   wp += (size_t)E * 4;
    int*   srcList = (int*)wp;   wp += (size_t)E * 4;
    int*   srcA    = (int*)wp;   wp += (size_t)E * 4;    // src node, dst-CSR order
    int*   dstB    = (int*)wp;   wp += (size_t)E * 4;    // dst node, src-CSR order
    float* invD    = (float*)wp; wp += (size_t)E * 4;    // 1/dx, dst-CSR order
    float* invS    = (float*)wp; wp += (size_t)E * 4;    // 1/dx, src-CSR order
    float* slopeD  = (float*)wp; wp += (size_t)E * 4;    // dz/dx, dst-CSR order
    int*   dstOff  = (int*)wp;   wp += (size_t)(N + 1) * 4;
    int*   srcOff  = (int*)wp;   wp += (size_t)(N + 1) * 4;
    int*   dstCnt  = (int*)wp;   wp += (size_t)N * 4;
    int*   srcCnt  = (int*)wp;   wp += (size_t)N * 4;
    int*   cursD   = (int*)wp;   wp += (size_t)N * 4;
    int*   cursS   = (int*)wp;   wp += (size_t)N * 4;
    int*   bsD     = (int*)wp;   wp += 512 * 4;
    int*   bsS     = (int*)wp;   wp += 512 * 4;
    int*   leafOff = (int*)wp;   wp += 2048 * 4;
    int*   leafN   = (int*)wp;   wp += 2048 * 4;
    int*   nLeaf   = (int*)wp;   wp += 64;
    float* partial = (float*)wp; wp += 2048 * 4;
    float* x = (float*)d_out;
    int*   ctr = (int*)(scal + 32);

    hipMemsetAsync(scal, 0, 64 * 4, stream);
    hipMemsetAsync(dstCnt, 0, (size_t)N * 4, stream);
    hipMemsetAsync(srcCnt, 0, (size_t)N * 4, stream);
    hipMemsetAsync(cursD, 0, (size_t)N * 4, stream);
    hipMemsetAsync(cursS, 0, (size_t)N * 4, stream);

    const int bn = 256;
    const int gN  = (N + bn - 1) / bn;
    const int gE  = (E + bn - 1) / bn;
    const int nb  = (N + 511) / 512;
    const int n4  = NF / 4;
    const int g4  = (n4 + bn - 1) / bn;
    const int N2  = NF / 4;            // (node, feature-half) threads
    const int g2  = (N2 + bn - 1) / bn;

    // ---- CSR build (stable by edge id) ----
    k_edge_pre<<<gE, bn, 0, stream>>>(dstp, srcp, dstCnt, srcCnt, E);
    k_scan1<<<nb, 512, 0, stream>>>(dstCnt, dstOff, bsD, N);
    k_scan2<<<1, 512, 0, stream>>>(bsD, nb);
    k_scan3<<<nb, 512, 0, stream>>>(dstOff, bsD, dstCnt, N, E);
    k_scan1<<<nb, 512, 0, stream>>>(srcCnt, srcOff, bsS, N);
    k_scan2<<<1, 512, 0, stream>>>(bsS, nb);
    k_scan3<<<nb, 512, 0, stream>>>(srcOff, bsS, srcCnt, N, E);
    k_fill<<<gE, bn, 0, stream>>>(dstp, srcp, dstOff, srcOff, cursD, cursS,
                                  dstList, srcList, E);
    k_sort<<<gN, bn, 0, stream>>>(dstOff, srcOff, dstList, srcList, N);
    k_perm<<<gE, bn, 0, stream>>>(dstList, srcList, srcp, dstp, ea,
                                  srcA, invD, slopeD, dstB, invS, E);
    k_build_leaves<<<1, 64, 0, stream>>>(NF - 1, leafOff, leafN, nLeaf);

    // ---- setup: b->r, y=u*b ; p = b + dt*D1T(y) ; r=p, x=0 ; rs0 = p.p ----
    k_slope_b<<<gN, bn, 0, stream>>>(u, slopeD, dstOff, r, y, dtp, gp, N);
    k_d1tz<<<g2, bn, 0, stream>>>(dstB, dstOff, invD, srcOff, invS,
                                  y, r, p, dtp, N2);
    k_init<<<g4, bn, 0, stream>>>((const float4*)p, (float4*)r, (float4*)x, n4);
    k_dot<<<DOT_NB, 64, 0, stream>>>(p, p, leafOff, leafN, nLeaf, partial, ctr,
                                     scal, NF - 1, 0, DOT_NB);

    // ---- CG loop ----
    for (int it = 0; it < CG_ITERS; ++it) {
        k_d1w<<<g2, bn, 0, stream>>>(srcA, dstOff, invD, p, u, w, y, dtp, N2);
        k_d1tz<<<g2, bn, 0, stream>>>(dstB, dstOff, invD, srcOff, invS,
                                      y, w, t, dtp, N2);
        k_dot<<<DOT_NB, 64, 0, stream>>>(p, t, leafOff, leafN, nLeaf, partial,
                                         ctr, scal, NF - 1, 1, DOT_NB);
        k_xr<<<g4, bn, 0, stream>>>((float4*)x, (float4*)r, (const float4*)p,
                                    (const float4*)t, scal, n4);
        k_dot<<<DOT_NB, 64, 0, stream>>>(r, r, leafOff, leafN, nLeaf, partial,
                                         ctr, scal, NF - 1, 2, DOT_NB);
        k_p<<<g4, bn, 0, stream>>>((float4*)p, (const float4*)r, scal, n4);
    }
}

// Round 2
// 8561.280 us; speedup vs baseline: 3.0387x; 2.3849x over previous
//
#include <hip/hip_runtime.h>
#include <math.h>

// PhysicsLSGStep: bitwise-faithful f32 replication of the numpy reference.
// R13: dot restructure. The numpy pairwise tree is FIXED for the launch, so:
//  - k_build_sched precomputes (once) each leaf's base-block list + combine
//    tree as (A,B) add triples with depths, and the upper tree likewise, by
//    replaying the exact same stack recursion symbolically.
//  - k_dot_leaf evaluates leaf trees level-parallel (adds at equal depth are
//    independent => parallel eval is value-identical; pairings unchanged).
//  - k_dot_fin (1 block) does the upper combine level-parallel + scal update.
//    The 800-block atomic ctr/isLast protocol is GONE (19.75ms outlier source).
// Scatter sums stay in sorted-edge-id (CSR) order; elementwise f32 __f*_rn.

#define F 8
#define CG_ITERS 30
#define LEAF_T 4096
#define LEAF_PAD (LEAF_T + LEAF_T / 128 + 8)
#define DOT_NB 800     // >= max leaves (NL <= 784 for NF-1 = 1,599,999)
#define ENC_ADD 1024   // operand encoding: <1024 = base slot, else add t+1024
#define BW_D 24        // max stack depth (upper tree needs ~12)

#define S_RS    0
#define S_ALPHA 1
#define S_BETA  2
#define S_DONE  3
#define S_DONE2 4

__device__ __forceinline__ float dt_eff_of(const float* dtp) {
    return fminf(fmaxf(dtp[0], 0.02f), 2.0f);
}

__device__ __forceinline__ int slotOf(int e, int NB) {
    return (e < ENC_ADD) ? e : (NB + (e - ENC_ADD));
}

// ---------- numpy pairwise sum base block from padded LDS (n<=128) ----------
__device__ __forceinline__ float pw_base_lds(const float* sA, const float* sB,
                                             int off, int n) {
#define AV(i) sA[(off + (i)) + ((off + (i)) >> 7)]
#define BV(i) sB[(off + (i)) + ((off + (i)) >> 7)]
    if (n < 8) {
        float res = 0.f;
        for (int i = 0; i < n; ++i) res = __fadd_rn(res, __fmul_rn(AV(i), BV(i)));
        return res;
    }
    float r0 = __fmul_rn(AV(0), BV(0));
    float r1 = __fmul_rn(AV(1), BV(1));
    float r2 = __fmul_rn(AV(2), BV(2));
    float r3 = __fmul_rn(AV(3), BV(3));
    float r4 = __fmul_rn(AV(4), BV(4));
    float r5 = __fmul_rn(AV(5), BV(5));
    float r6 = __fmul_rn(AV(6), BV(6));
    float r7 = __fmul_rn(AV(7), BV(7));
    int i = 8;
    int lim = n - (n & 7);
    for (; i < lim; i += 8) {
        r0 = __fadd_rn(r0, __fmul_rn(AV(i + 0), BV(i + 0)));
        r1 = __fadd_rn(r1, __fmul_rn(AV(i + 1), BV(i + 1)));
        r2 = __fadd_rn(r2, __fmul_rn(AV(i + 2), BV(i + 2)));
        r3 = __fadd_rn(r3, __fmul_rn(AV(i + 3), BV(i + 3)));
        r4 = __fadd_rn(r4, __fmul_rn(AV(i + 4), BV(i + 4)));
        r5 = __fadd_rn(r5, __fmul_rn(AV(i + 5), BV(i + 5)));
        r6 = __fadd_rn(r6, __fmul_rn(AV(i + 6), BV(i + 6)));
        r7 = __fadd_rn(r7, __fmul_rn(AV(i + 7), BV(i + 7)));
    }
    float res = __fadd_rn(__fadd_rn(__fadd_rn(r0, r1), __fadd_rn(r2, r3)),
                          __fadd_rn(__fadd_rn(r4, r5), __fadd_rn(r6, r7)));
    for (; i < n; ++i) res = __fadd_rn(res, __fmul_rn(AV(i), BV(i)));
    return res;
#undef AV
#undef BV
}

// leaf decomposition of virtual [0, n) (n = NF-1; physical offset +1).
__global__ void k_build_leaves(int n, int* leafOff, int* leafN, int* nLeaf) {
    __shared__ int spOff[40], spN[40];
    if (threadIdx.x != 0 || blockIdx.x != 0) return;
    int sp = 0;
    spOff[0] = 0; spN[0] = n;
    int cnt = 0;
    while (sp >= 0) {
        int off = spOff[sp], nn = spN[sp]; sp--;
        if (nn <= LEAF_T) {
            if (cnt < 2048) { leafOff[cnt] = off; leafN[cnt] = nn; }
            cnt++;
        } else {
            int n2 = nn / 2; n2 -= (n2 & 7);
            spOff[++sp] = off + n2; spN[sp] = nn - n2;  // right (popped second)
            spOff[++sp] = off;      spN[sp] = n2;       // left  (popped first)
        }
    }
    *nLeaf = cnt;
}

// Symbolic replay of the pairwise recursion. Emits base blocks (in left-to-
// right order) and add triples (post-order), with depths. LDS stacks, stride 64.
__device__ void build_tree(int n, int T, int tid,
                           int* so, int* sn_, int* st, int* sid, int* sdp,
                           int* bOffOut, int* bNOut,
                           int* AOut, int* BOut, int* depOut,
                           int* pNB, int* pNT, int* pMaxD) {
    int sp = 0, coff = 0, cn = n, c2 = 0, t = 0;
    int rootd = 0;
    for (;;) {
        if (cn <= T) {
            if (bOffOut) { bOffOut[c2] = coff; bNOut[c2] = cn; }
            int id = c2, dep = 0; c2++;
            bool fin = false;
            for (;;) {
                if (sp == 0) { rootd = dep; fin = true; break; }
                int q = (sp - 1) * 64 + tid;
                if (st[q] == 0) {
                    st[q] = 1; sid[q] = id; sdp[q] = dep;
                    int n2 = sn_[q] / 2; n2 -= (n2 & 7);
                    coff = so[q] + n2; cn = sn_[q] - n2;
                    break;
                } else {
                    AOut[t] = sid[q]; BOut[t] = id;   // add = stored(left)+cur(right)
                    int dA = sdp[q];
                    dep = ((dA > dep) ? dA : dep) + 1;
                    depOut[t] = dep;
                    id = ENC_ADD + t; t++;
                    sp--;
                }
            }
            if (fin) break;
        } else {
            int q = sp * 64 + tid;
            so[q] = coff; sn_[q] = cn; st[q] = 0; sp++;
            int n2 = cn / 2; n2 -= (n2 & 7);
            cn = n2;
        }
    }
    *pNB = c2; *pNT = t; *pMaxD = rootd;
}

// depth-bucket the adds into evaluation order (level-parallel schedule)
__device__ void bucketize(const int* depArr, int NT, int maxD, int tid,
                          int* cnt, int* orderOut, int* levOffOut) {
    for (int d = 0; d <= maxD; ++d) cnt[d * 64 + tid] = 0;
    for (int t = 0; t < NT; ++t) cnt[depArr[t] * 64 + tid]++;
    int run = 0;
    levOffOut[0] = 0;
    for (int d = 1; d <= maxD; ++d) { run += cnt[d * 64 + tid]; levOffOut[d] = run; }
    for (int d = 1; d <= maxD; ++d) cnt[d * 64 + tid] = levOffOut[d - 1];
    for (int t = 0; t < NT; ++t) { int d = depArr[t]; orderOut[cnt[d * 64 + tid]++] = t; }
}

// one-shot schedule build: one thread per leaf; thread 0 also builds upper tree
__global__ void k_build_sched(const int* __restrict__ leafN, const int* __restrict__ nLeaf,
                              int* lNB, int* lBOff, int* lBN, int* lA, int* lB,
                              int* lDep, int* lOrder, int* lLevOff, int* lMaxD,
                              int* uHdr, int* uA, int* uB, int* uDep, int* uOrder,
                              int* uLevOff, int n) {
    __shared__ int sSo[BW_D * 64], sSn[BW_D * 64], sSt[BW_D * 64];
    __shared__ int sSid[BW_D * 64], sSdp[BW_D * 64];
    __shared__ int sCnt[32 * 64];
    int tid = threadIdx.x;
    int g = blockIdx.x * 64 + tid;
    int NL = *nLeaf; if (NL > 1024) NL = 1024;
    if (g < NL) {
        int NB, NT, maxD;
        build_tree(leafN[g], 128, tid, sSo, sSn, sSt, sSid, sSdp,
                   lBOff + g * 64, lBN + g * 64,
                   lA + g * 64, lB + g * 64, lDep + g * 64, &NB, &NT, &maxD);
        lNB[g] = NB; lMaxD[g] = maxD;
        bucketize(lDep + g * 64, NT, maxD, tid, sCnt, lOrder + g * 64,
                  lLevOff + g * 32);
    }
    if (g == 0) {
        int NB, NT, maxD;
        build_tree(n, LEAF_T, tid, sSo, sSn, sSt, sSid, sSdp,
                   (int*)0, (int*)0, uA, uB, uDep, &NB, &NT, &maxD);
        uHdr[0] = NT; uHdr[1] = maxD;
        bucketize(uDep, NT, maxD, tid, sCnt, uOrder, uLevOff);
    }
}

// per-leaf dot partial: stage -> base blocks (parallel) -> level-parallel tree
__global__ void k_dot_leaf(const float* __restrict__ a, const float* __restrict__ b,
                           const int* __restrict__ leafOff, const int* __restrict__ leafN,
                           const int* __restrict__ nLeaf,
                           const int* __restrict__ lNB, const int* __restrict__ lBOff,
                           const int* __restrict__ lBN, const int* __restrict__ lA,
                           const int* __restrict__ lB, const int* __restrict__ lOrder,
                           const int* __restrict__ lLevOff, const int* __restrict__ lMaxD,
                           float* __restrict__ partial) {
    __shared__ float sA[LEAF_PAD], sB[LEAF_PAD];
    __shared__ float sVal[160];
    int j = blockIdx.x, lane = threadIdx.x;
    if (j >= *nLeaf) return;
    int P = leafOff[j] + 1, nn = leafN[j];
    for (int g = lane; g < nn; g += 128) {
        float av = a[P + g], bv = b[P + g];
        int m = g + (g >> 7);
        sA[m] = av; sB[m] = bv;
    }
    __syncthreads();
    int NB = lNB[j];
    if (lane < NB) sVal[lane] = pw_base_lds(sA, sB, lBOff[j * 64 + lane],
                                            lBN[j * 64 + lane]);
    __syncthreads();
    int maxD = lMaxD[j];
    const int* LO = lLevOff + j * 32;
    for (int d = 1; d <= maxD; ++d) {
        int s0 = LO[d - 1], s1 = LO[d];
        for (int s = s0 + lane; s < s1; s += 128) {
            int tt = lOrder[j * 64 + s];
            int ia = slotOf(lA[j * 64 + tt], NB);
            int ib = slotOf(lB[j * 64 + tt], NB);
            sVal[NB + tt] = __fadd_rn(sVal[ia], sVal[ib]);
        }
        __syncthreads();
    }
    if (lane == 0) {
        int NT = NB - 1;
        partial[j] = (NT > 0) ? sVal[NB + NT - 1] : sVal[0];
    }
}

// upper combine (level-parallel) + scalar update. 1 block, 256 threads.
__global__ void k_dot_fin(const float* __restrict__ a, const float* __restrict__ b,
                          const float* __restrict__ partial, const int* __restrict__ nLeaf,
                          const int* __restrict__ uHdr, const int* __restrict__ uA,
                          const int* __restrict__ uB, const int* __restrict__ uOrder,
                          const int* __restrict__ uLevOff, float* __restrict__ scal,
                          int mode) {
    __shared__ float sVal[2048];
    int lane = threadIdx.x;
    int NL = *nLeaf;
    int NT = uHdr[0], maxD = uHdr[1];
    for (int k = lane; k < NL; k += 256) sVal[k] = partial[k];
    __syncthreads();
    for (int d = 1; d <= maxD; ++d) {
        int s0 = uLevOff[d - 1], s1 = uLevOff[d];
        for (int s = s0 + lane; s < s1; s += 256) {
            int tt = uOrder[s];
            sVal[NL + tt] = __fadd_rn(sVal[slotOf(uA[tt], NL)],
                                      sVal[slotOf(uB[tt], NL)]);
        }
        __syncthreads();
    }
    if (lane != 0) return;
    float res = (NT > 0) ? sVal[NL + NT - 1] : sVal[0];
    res = __fadd_rn(__fmul_rn(a[0], b[0]), res);   // first-element init
    if (mode == 0) {
        scal[S_RS] = res; scal[S_DONE] = 0.f; scal[S_DONE2] = 0.f;
    } else if (mode == 1) {
        scal[S_DONE] = scal[S_DONE2];  // done_old for this iteration
        scal[S_ALPHA] = __fdiv_rn(scal[S_RS], __fadd_rn(res, (float)1e-12));
    } else {
        float rs1 = res;
        scal[S_BETA] = __fdiv_rn(rs1, __fadd_rn(scal[S_RS], (float)1e-12));
        float dn = scal[S_DONE];
        if (dn == 0.f) scal[S_RS] = rs1;
        scal[S_DONE2] = (dn != 0.f || __fsqrt_rn(rs1) <= (float)1e-4) ? 1.f : 0.f;
    }
}

// ---------- CSR build (stable in edge order) ----------

__global__ void k_edge_pre(const int* __restrict__ dst, const int* __restrict__ src,
                           int* __restrict__ dstCnt, int* __restrict__ srcCnt, int E) {
    int e = blockIdx.x * blockDim.x + threadIdx.x;
    if (e >= E) return;
    atomicAdd(&dstCnt[dst[e]], 1);
    atomicAdd(&srcCnt[src[e]], 1);
}

__global__ void k_scan1(const int* __restrict__ cnt, int* __restrict__ incl,
                        int* __restrict__ bsums, int N) {
    __shared__ int sm[512];
    int i = blockIdx.x * 512 + threadIdx.x;
    sm[threadIdx.x] = (i < N) ? cnt[i] : 0;
    __syncthreads();
    for (int off = 1; off < 512; off <<= 1) {
        int t = (threadIdx.x >= off) ? sm[threadIdx.x - off] : 0;
        __syncthreads();
        sm[threadIdx.x] += t;
        __syncthreads();
    }
    if (i < N) incl[i] = sm[threadIdx.x];
    if (threadIdx.x == 511) bsums[blockIdx.x] = sm[511];
}

__global__ void k_scan2(int* __restrict__ bsums, int nb) {
    __shared__ int sm[512];
    sm[threadIdx.x] = (threadIdx.x < nb) ? bsums[threadIdx.x] : 0;
    __syncthreads();
    for (int off = 1; off < 512; off <<= 1) {
        int t = (threadIdx.x >= off) ? sm[threadIdx.x - off] : 0;
        __syncthreads();
        sm[threadIdx.x] += t;
        __syncthreads();
    }
    if (threadIdx.x < nb) bsums[threadIdx.x] = sm[threadIdx.x];
}

__global__ void k_scan3(int* __restrict__ off, const int* __restrict__ bsums,
                        const int* __restrict__ cnt, int N, int E) {
    int i = blockIdx.x * 512 + threadIdx.x;
    if (i < N) {
        int add = (blockIdx.x > 0) ? bsums[blockIdx.x - 1] : 0;
        off[i] = off[i] + add - cnt[i];  // exclusive
    }
    if (i == 0) off[N] = E;
}

__global__ void k_fill(const int* __restrict__ dst, const int* __restrict__ src,
                       const int* __restrict__ dstOff, const int* __restrict__ srcOff,
                       int* __restrict__ cursD, int* __restrict__ cursS,
                       int* __restrict__ dstList, int* __restrict__ srcList, int E) {
    int e = blockIdx.x * blockDim.x + threadIdx.x;
    if (e >= E) return;
    int d = dst[e];
    dstList[dstOff[d] + atomicAdd(&cursD[d], 1)] = e;
    int s0 = src[e];
    srcList[srcOff[s0] + atomicAdd(&cursS[s0], 1)] = e;
}

__device__ __forceinline__ void insort(int* L, int lo, int hi) {
    for (int a = lo + 1; a < hi; ++a) {
        int key = L[a]; int b = a - 1;
        while (b >= lo && L[b] > key) { L[b + 1] = L[b]; b--; }
        L[b + 1] = key;
    }
}

__global__ void k_sort(const int* __restrict__ dstOff, const int* __restrict__ srcOff,
                       int* __restrict__ dstList, int* __restrict__ srcList, int N) {
    int i = blockIdx.x * blockDim.x + threadIdx.x;
    if (i >= N) return;
    insort(dstList, dstOff[i], dstOff[i + 1]);
    insort(srcList, srcOff[i], srcOff[i + 1]);
}

// Permute per-edge operands into CSR order, IN PLACE over the lists
// (read both ids, then overwrite: dstList becomes srcA, srcList becomes dstB).
// Same fmaxf+__fdiv_rn ops as before => downstream arithmetic bit-identical.
__global__ void k_perm(int* dstList, int* srcList,
                       const int* __restrict__ srcp, const int* __restrict__ dstp,
                       const float* __restrict__ ea,
                       float* __restrict__ invD, float* __restrict__ slopeD,
                       float* __restrict__ invS, int E) {
    int k = blockIdx.x * blockDim.x + threadIdx.x;
    if (k >= E) return;
    int e  = dstList[k];
    int e2 = srcList[k];
    float dx  = fmaxf(ea[2 * e], 1e-6f);
    float dx2 = fmaxf(ea[2 * e2], 1e-6f);
    int sA_ = srcp[e];
    int dB_ = dstp[e2];
    float iD = __fdiv_rn(1.f, dx);
    float sD = __fdiv_rn(ea[2 * e + 1], dx);
    float iS = __fdiv_rn(1.f, dx2);
    dstList[k] = sA_;    // srcA
    srcList[k] = dB_;    // dstB
    invD[k] = iD; slopeD[k] = sD; invS[k] = iS;
}

// ---------- physics kernels (exact np op order, f32 sequential) ----------

__global__ void k_slope_b(const float* __restrict__ u, const float* __restrict__ slopeD,
                          const int* __restrict__ dstOff,
                          float* __restrict__ r, float* __restrict__ y,
                          const float* __restrict__ dtp, const float* __restrict__ gp,
                          int N) {
    int i = blockIdx.x * blockDim.x + threadIdx.x;
    if (i >= N) return;
    float dtg = __fmul_rn(dt_eff_of(dtp), gp[0]);
    float sn = 0.f;
    int k0 = dstOff[i], k1 = dstOff[i + 1];
    for (int k = k0; k < k1; ++k) sn = __fadd_rn(sn, slopeD[k]);
    float ms = __fmul_rn(dtg, sn);
    const float4* u4 = (const float4*)u;
    float4* r4 = (float4*)r;
    float4* y4 = (float4*)y;
    #pragma unroll
    for (int hh = 0; hh < 2; ++hh) {
        float4 uv = u4[i * 2 + hh];
        float4 bv;
        bv.x = __fsub_rn(uv.x, ms);
        bv.y = __fsub_rn(uv.y, ms);
        bv.z = __fsub_rn(uv.z, ms);
        bv.w = __fsub_rn(uv.w, ms);
        r4[i * 2 + hh] = bv;
        float4 yv;
        yv.x = __fmul_rn(uv.x, bv.x);
        yv.y = __fmul_rn(uv.y, bv.y);
        yv.z = __fmul_rn(uv.z, bv.z);
        yv.w = __fmul_rn(uv.w, bv.w);
        y4[i * 2 + hh] = yv;
    }
}

__global__ void k_d1tz(const int* __restrict__ dstB, const int* __restrict__ dstOff,
                       const float* __restrict__ invD, const int* __restrict__ srcOff,
                       const float* __restrict__ invS, const float* __restrict__ y,
                       const float* __restrict__ base, float* __restrict__ out,
                       const float* __restrict__ dtp, int N2) {
    int idx2 = blockIdx.x * blockDim.x + threadIdx.x;
    if (idx2 >= N2) return;
    int i = idx2 >> 1, h = idx2 & 1;
    const float4* y4 = (const float4*)y;
    float4 uy = y4[idx2];
    float4 acc = make_float4(0.f, 0.f, 0.f, 0.f);
    int k0 = dstOff[i], k1 = dstOff[i + 1];
    for (int k = k0; k < k1; ++k) {
        float iv = invD[k];
        acc.x = __fadd_rn(acc.x, __fmul_rn(uy.x, iv));
        acc.y = __fadd_rn(acc.y, __fmul_rn(uy.y, iv));
        acc.z = __fadd_rn(acc.z, __fmul_rn(uy.z, iv));
        acc.w = __fadd_rn(acc.w, __fmul_rn(uy.w, iv));
    }
    k0 = srcOff[i]; k1 = srcOff[i + 1];
    for (int k = k0; k < k1; ++k) {
        int d = dstB[k];
        float iv = invS[k];
        float4 yd = y4[d * 2 + h];
        float t0 = __fmul_rn(yd.x, iv); acc.x = __fadd_rn(acc.x, -t0);
        float t1 = __fmul_rn(yd.y, iv); acc.y = __fadd_rn(acc.y, -t1);
        float t2 = __fmul_rn(yd.z, iv); acc.z = __fadd_rn(acc.z, -t2);
        float t3 = __fmul_rn(yd.w, iv); acc.w = __fadd_rn(acc.w, -t3);
    }
    float dt = dt_eff_of(dtp);
    float4 bs = ((const float4*)base)[idx2];
    float4 ov;
    ov.x = __fadd_rn(bs.x, __fmul_rn(dt, acc.x));
    ov.y = __fadd_rn(bs.y, __fmul_rn(dt, acc.y));
    ov.z = __fadd_rn(bs.z, __fmul_rn(dt, acc.z));
    ov.w = __fadd_rn(bs.w, __fmul_rn(dt, acc.w));
    ((float4*)out)[idx2] = ov;
}

__global__ void k_init(const float4* __restrict__ p4, float4* __restrict__ r4,
                       float4* __restrict__ x4, int n4) {
    int i = blockIdx.x * blockDim.x + threadIdx.x;
    if (i >= n4) return;
    r4[i] = p4[i];
    x4[i] = make_float4(0.f, 0.f, 0.f, 0.f);
}

__global__ void k_d1w(const int* __restrict__ srcA, const int* __restrict__ dstOff,
                      const float* __restrict__ invD, const float* __restrict__ pv,
                      const float* __restrict__ u,
                      float* __restrict__ w, float* __restrict__ y,
                      const float* __restrict__ dtp, int N2) {
    int idx2 = blockIdx.x * blockDim.x + threadIdx.x;
    if (idx2 >= N2) return;
    int i = idx2 >> 1, h = idx2 & 1;
    const float4* pv4 = (const float4*)pv;
    float4 pi = pv4[idx2];
    float4 acc = make_float4(0.f, 0.f, 0.f, 0.f);
    int k0 = dstOff[i], k1 = dstOff[i + 1];
    for (int k = k0; k < k1; ++k) {
        int s = srcA[k];
        float iv = invD[k];
        float4 ps = pv4[s * 2 + h];
        acc.x = __fadd_rn(acc.x, __fmul_rn(__fsub_rn(pi.x, ps.x), iv));
        acc.y = __fadd_rn(acc.y, __fmul_rn(__fsub_rn(pi.y, ps.y), iv));
        acc.z = __fadd_rn(acc.z, __fmul_rn(__fsub_rn(pi.z, ps.z), iv));
        acc.w = __fadd_rn(acc.w, __fmul_rn(__fsub_rn(pi.w, ps.w), iv));
    }
    float dt = dt_eff_of(dtp);
    float4 uv = ((const float4*)u)[idx2];
    float4 wv;
    wv.x = __fadd_rn(pi.x, __fmul_rn(dt, __fmul_rn(uv.x, acc.x)));
    wv.y = __fadd_rn(pi.y, __fmul_rn(dt, __fmul_rn(uv.y, acc.y)));
    wv.z = __fadd_rn(pi.z, __fmul_rn(dt, __fmul_rn(uv.z, acc.z)));
    wv.w = __fadd_rn(pi.w, __fmul_rn(dt, __fmul_rn(uv.w, acc.w)));
    ((float4*)w)[idx2] = wv;
    float4 yv;
    yv.x = __fmul_rn(uv.x, wv.x);
    yv.y = __fmul_rn(uv.y, wv.y);
    yv.z = __fmul_rn(uv.z, wv.z);
    yv.w = __fmul_rn(uv.w, wv.w);
    ((float4*)y)[idx2] = yv;
}

__global__ void k_xr(float4* __restrict__ x4, float4* __restrict__ r4,
                     const float4* __restrict__ p4, const float4* __restrict__ z4,
                     const float* __restrict__ scal, int n4) {
    int i = blockIdx.x * blockDim.x + threadIdx.x;
    if (i >= n4) return;
    if (scal[S_DONE] != 0.f) return;
    float al = scal[S_ALPHA];
    float4 xv = x4[i], pv = p4[i], rv = r4[i], zv = z4[i];
    xv.x = __fadd_rn(xv.x, __fmul_rn(al, pv.x));
    xv.y = __fadd_rn(xv.y, __fmul_rn(al, pv.y));
    xv.z = __fadd_rn(xv.z, __fmul_rn(al, pv.z));
    xv.w = __fadd_rn(xv.w, __fmul_rn(al, pv.w));
    rv.x = __fsub_rn(rv.x, __fmul_rn(al, zv.x));
    rv.y = __fsub_rn(rv.y, __fmul_rn(al, zv.y));
    rv.z = __fsub_rn(rv.z, __fmul_rn(al, zv.z));
    rv.w = __fsub_rn(rv.w, __fmul_rn(al, zv.w));
    x4[i] = xv;
    r4[i] = rv;
}

__global__ void k_p(float4* __restrict__ p4, const float4* __restrict__ r4,
                    const float* __restrict__ scal, int n4) {
    int i = blockIdx.x * blockDim.x + threadIdx.x;
    if (i >= n4) return;
    if (scal[S_DONE] != 0.f) return;
    float be = scal[S_BETA];
    float4 pv = p4[i], rv = r4[i];
    pv.x = __fadd_rn(rv.x, __fmul_rn(be, pv.x));
    pv.y = __fadd_rn(rv.y, __fmul_rn(be, pv.y));
    pv.z = __fadd_rn(rv.z, __fmul_rn(be, pv.z));
    pv.w = __fadd_rn(rv.w, __fmul_rn(be, pv.w));
    p4[i] = pv;
}

extern "C" void kernel_launch(void* const* d_in, const int* in_sizes, int n_in,
                              void* d_out, int out_size, void* d_ws, size_t ws_size,
                              hipStream_t stream) {
    const float* u   = (const float*)d_in[0];
    const int*   ei  = (const int*)d_in[1];
    const float* ea  = (const float*)d_in[2];
    const float* dtp = (const float*)d_in[3];
    const float* gp  = (const float*)d_in[4];

    const int NF = in_sizes[0];        // 1,600,000
    const int N  = NF / F;             // 200,000
    const int E  = in_sizes[2] / 2;    // 3,200,000
    const int* srcp = ei;
    const int* dstp = ei + E;

    char* wp = (char*)d_ws;
    float* scal    = (float*)wp; wp += 64 * 4;
    float* r       = (float*)wp; wp += (size_t)NF * 4;
    float* p       = (float*)wp; wp += (size_t)NF * 4;
    float* t       = (float*)wp; wp += (size_t)NF * 4;   // z
    float* w       = (float*)wp; wp += (size_t)NF * 4;
    float* y       = (float*)wp; wp += (size_t)NF * 4;   // u*w / u*b
    int*   dstList = (int*)wp;   wp += (size_t)E * 4;    // becomes srcA after k_perm
    int*   srcList = (int*)wp;   wp += (size_t)E * 4;    // becomes dstB after k_perm
    float* invD    = (float*)wp; wp += (size_t)E * 4;
    float* invS    = (float*)wp; wp += (size_t)E * 4;
    float* slopeD  = (float*)wp; wp += (size_t)E * 4;
    int*   dstOff  = (int*)wp;   wp += (size_t)(N + 1) * 4;
    int*   srcOff  = (int*)wp;   wp += (size_t)(N + 1) * 4;
    int*   dstCnt  = (int*)wp;   wp += (size_t)N * 4;
    int*   srcCnt  = (int*)wp;   wp += (size_t)N * 4;
    int*   cursD   = (int*)wp;   wp += (size_t)N * 4;
    int*   cursS   = (int*)wp;   wp += (size_t)N * 4;
    int*   bsD     = (int*)wp;   wp += 512 * 4;
    int*   bsS     = (int*)wp;   wp += 512 * 4;
    int*   leafOff = (int*)wp;   wp += 2048 * 4;
    int*   leafN   = (int*)wp;   wp += 2048 * 4;
    int*   nLeaf   = (int*)wp;   wp += 64;
    float* partial = (float*)wp; wp += 2048 * 4;
    // dot schedules (built once)
    int*   lNB     = (int*)wp;   wp += 1024 * 4;
    int*   lMaxD   = (int*)wp;   wp += 1024 * 4;
    int*   lBOff   = (int*)wp;   wp += (size_t)1024 * 64 * 4;
    int*   lBN     = (int*)wp;   wp += (size_t)1024 * 64 * 4;
    int*   lA      = (int*)wp;   wp += (size_t)1024 * 64 * 4;
    int*   lB      = (int*)wp;   wp += (size_t)1024 * 64 * 4;
    int*   lDep    = (int*)wp;   wp += (size_t)1024 * 64 * 4;
    int*   lOrder  = (int*)wp;   wp += (size_t)1024 * 64 * 4;
    int*   lLevOff = (int*)wp;   wp += (size_t)1024 * 32 * 4;
    int*   uHdr    = (int*)wp;   wp += 64;
    int*   uA      = (int*)wp;   wp += 1024 * 4;
    int*   uB      = (int*)wp;   wp += 1024 * 4;
    int*   uDep    = (int*)wp;   wp += 1024 * 4;
    int*   uOrder  = (int*)wp;   wp += 1024 * 4;
    int*   uLevOff = (int*)wp;   wp += 64 * 4;
    float* x = (float*)d_out;

    hipMemsetAsync(scal, 0, 64 * 4, stream);
    hipMemsetAsync(dstCnt, 0, (size_t)N * 4, stream);
    hipMemsetAsync(srcCnt, 0, (size_t)N * 4, stream);
    hipMemsetAsync(cursD, 0, (size_t)N * 4, stream);
    hipMemsetAsync(cursS, 0, (size_t)N * 4, stream);

    const int bn = 256;
    const int gN  = (N + bn - 1) / bn;
    const int gE  = (E + bn - 1) / bn;
    const int nb  = (N + 511) / 512;
    const int n4  = NF / 4;
    const int g4  = (n4 + bn - 1) / bn;
    const int N2  = NF / 4;            // (node, feature-half) threads
    const int g2  = (N2 + bn - 1) / bn;

    // ---- CSR build (stable by edge id) ----
    k_edge_pre<<<gE, bn, 0, stream>>>(dstp, srcp, dstCnt, srcCnt, E);
    k_scan1<<<nb, 512, 0, stream>>>(dstCnt, dstOff, bsD, N);
    k_scan2<<<1, 512, 0, stream>>>(bsD, nb);
    k_scan3<<<nb, 512, 0, stream>>>(dstOff, bsD, dstCnt, N, E);
    k_scan1<<<nb, 512, 0, stream>>>(srcCnt, srcOff, bsS, N);
    k_scan2<<<1, 512, 0, stream>>>(bsS, nb);
    k_scan3<<<nb, 512, 0, stream>>>(srcOff, bsS, srcCnt, N, E);
    k_fill<<<gE, bn, 0, stream>>>(dstp, srcp, dstOff, srcOff, cursD, cursS,
                                  dstList, srcList, E);
    k_sort<<<gN, bn, 0, stream>>>(dstOff, srcOff, dstList, srcList, N);
    k_perm<<<gE, bn, 0, stream>>>(dstList, srcList, srcp, dstp, ea,
                                  invD, slopeD, invS, E);
    k_build_leaves<<<1, 64, 0, stream>>>(NF - 1, leafOff, leafN, nLeaf);
    k_build_sched<<<16, 64, 0, stream>>>(leafN, nLeaf, lNB, lBOff, lBN, lA, lB,
                                         lDep, lOrder, lLevOff, lMaxD,
                                         uHdr, uA, uB, uDep, uOrder, uLevOff,
                                         NF - 1);
    const int* srcA = dstList;   // after k_perm
    const int* dstB = srcList;   // after k_perm

    // ---- setup: b->r, y=u*b ; p = b + dt*D1T(y) ; r=p, x=0 ; rs0 = p.p ----
    k_slope_b<<<gN, bn, 0, stream>>>(u, slopeD, dstOff, r, y, dtp, gp, N);
    k_d1tz<<<g2, bn, 0, stream>>>(dstB, dstOff, invD, srcOff, invS,
                                  y, r, p, dtp, N2);
    k_init<<<g4, bn, 0, stream>>>((const float4*)p, (float4*)r, (float4*)x, n4);
    k_dot_leaf<<<DOT_NB, 128, 0, stream>>>(p, p, leafOff, leafN, nLeaf, lNB,
                                           lBOff, lBN, lA, lB, lOrder, lLevOff,
                                           lMaxD, partial);
    k_dot_fin<<<1, 256, 0, stream>>>(p, p, partial, nLeaf, uHdr, uA, uB,
                                     uOrder, uLevOff, scal, 0);

    // ---- CG loop ----
    for (int it = 0; it < CG_ITERS; ++it) {
        k_d1w<<<g2, bn, 0, stream>>>(srcA, dstOff, invD, p, u, w, y, dtp, N2);
        k_d1tz<<<g2, bn, 0, stream>>>(dstB, dstOff, invD, srcOff, invS,
                                      y, w, t, dtp, N2);
        k_dot_leaf<<<DOT_NB, 128, 0, stream>>>(p, t, leafOff, leafN, nLeaf, lNB,
                                               lBOff, lBN, lA, lB, lOrder,
                                               lLevOff, lMaxD, partial);
        k_dot_fin<<<1, 256, 0, stream>>>(p, t, partial, nLeaf, uHdr, uA, uB,
                                         uOrder, uLevOff, scal, 1);
        k_xr<<<g4, bn, 0, stream>>>((float4*)x, (float4*)r, (const float4*)p,
                                    (const float4*)t, scal, n4);
        k_dot_leaf<<<DOT_NB, 128, 0, stream>>>(r, r, leafOff, leafN, nLeaf, lNB,
                                               lBOff, lBN, lA, lB, lOrder,
                                               lLevOff, lMaxD, partial);
        k_dot_fin<<<1, 256, 0, stream>>>(r, r, partial, nLeaf, uHdr, uA, uB,
                                         uOrder, uLevOff, scal, 2);
        k_p<<<g4, bn, 0, stream>>>((float4*)p, (const float4*)r, scal, n4);
    }
}